// Round 1
// baseline (147.757 us; speedup 1.0000x reference)
//
#include <hip/hip_runtime.h>

#define IMG_H 2048
#define IMG_W 2048
#define IMG_B 8
#define GY 8
#define GX 8
#define TH 256
#define TW 256
#define NB 256
#define AREA (TH*TW)         // 65536
#define CLIP_LIM 1024        // max(int(4.0*65536/256),1)

// ---------------- Kernel 1: per-tile histogram -> clipped/redistributed -> cdf -> LUT
__global__ __launch_bounds__(256) void clahe_hist_lut(const float* __restrict__ img,
                                                      float* __restrict__ lut) {
    const int t   = blockIdx.x;          // 0..511  (b*64 + ty*8 + tx)
    const int b   = t >> 6;
    const int ty  = (t >> 3) & 7;
    const int tx  = t & 7;
    const int tid = threadIdx.x;
    const int wv  = tid >> 6;            // wave id 0..3

    __shared__ int h[4][NB];             // per-wave sub-histograms (4 KB)
    __shared__ int c[NB];
    __shared__ int s_excess;

    h[0][tid] = 0; h[1][tid] = 0; h[2][tid] = 0; h[3][tid] = 0;
    if (tid == 0) s_excess = 0;
    __syncthreads();

    const float* base = img + (size_t)b * (IMG_H * IMG_W)
                            + (size_t)(ty * TH) * IMG_W + tx * TW;

    // 65536 px / tile = 16384 float4; 64 iterations of 256 threads, coalesced
    for (int i = tid; i < (AREA / 4); i += 256) {
        const int r = i >> 6;            // row within tile
        const int q = i & 63;            // float4 column
        const float4 v = *reinterpret_cast<const float4*>(base + (size_t)r * IMG_W + q * 4);
        atomicAdd(&h[wv][(int)fminf(fmaxf(v.x, 0.f), 255.f)], 1);
        atomicAdd(&h[wv][(int)fminf(fmaxf(v.y, 0.f), 255.f)], 1);
        atomicAdd(&h[wv][(int)fminf(fmaxf(v.z, 0.f), 255.f)], 1);
        atomicAdd(&h[wv][(int)fminf(fmaxf(v.w, 0.f), 255.f)], 1);
    }
    __syncthreads();

    const int sum     = h[0][tid] + h[1][tid] + h[2][tid] + h[3][tid];
    int clipped       = min(sum, CLIP_LIM);
    atomicAdd(&s_excess, sum - clipped);
    __syncthreads();

    const int excess   = s_excess;
    const int add      = excess >> 8;        // excess / 256
    const int residual = excess & 255;       // excess % 256
    int step = 256 / (residual > 0 ? residual : 1);
    if (step < 1) step = 1;
    clipped += add + ((residual > 0 && (tid % step) == 0) ? 1 : 0);
    c[tid] = clipped;
    __syncthreads();

    // inclusive Hillis-Steele scan over 256 bins
    #pragma unroll
    for (int off = 1; off < NB; off <<= 1) {
        const int v = (tid >= off) ? c[tid - off] : 0;
        __syncthreads();
        c[tid] += v;
        __syncthreads();
    }

    float lv = rintf((float)c[tid] * (255.0f / (float)AREA));  // round-half-even, exact 255/2^16
    lv = fminf(fmaxf(lv, 0.f), 255.f);
    lut[t * NB + tid] = lv;
}

// ---------------- Kernel 2: bilinear LUT apply, 4 px/thread
__global__ __launch_bounds__(256) void clahe_apply(const float* __restrict__ img,
                                                   const float* __restrict__ lut,
                                                   float* __restrict__ out) {
    const size_t p = ((size_t)blockIdx.x * 256 + threadIdx.x) * 4;   // pixel base
    const int b   = (int)(p >> 22);          // H*W = 2^22
    const int rem = (int)(p & 4194303);
    const int y   = rem >> 11;               // W = 2^11
    const int x0  = rem & 2047;

    // y interpolation params (constant per thread)
    const float yf  = (float)y * (1.0f / 256.0f) - 0.5f;
    const float y1f = floorf(yf);
    const float ya  = yf - y1f;
    const int y1 = min(max((int)y1f, 0), 7);
    const int y2 = min(max((int)y1f + 1, 0), 7);

    // x tile indices constant within an aligned float4 (boundaries at x%256==128, all %4==0)
    const float xf0 = (float)x0 * (1.0f / 256.0f) - 0.5f;
    const float x1f = floorf(xf0);
    const int x1 = min(max((int)x1f, 0), 7);
    const int x2 = min(max((int)x1f + 1, 0), 7);

    const float* lb = lut + (size_t)b * (GY * GX * NB);
    const float* __restrict__ l_11 = lb + (y1 * 8 + x1) * NB;
    const float* __restrict__ l_12 = lb + (y1 * 8 + x2) * NB;
    const float* __restrict__ l_21 = lb + (y2 * 8 + x1) * NB;
    const float* __restrict__ l_22 = lb + (y2 * 8 + x2) * NB;

    const float4 v = *reinterpret_cast<const float4*>(img + p);
    const float vals[4] = {v.x, v.y, v.z, v.w};
    float res[4];
    #pragma unroll
    for (int j = 0; j < 4; ++j) {
        const float xf = (float)(x0 + j) * (1.0f / 256.0f) - 0.5f;
        const float xa = xf - x1f;
        const int bin  = (int)fminf(fmaxf(vals[j], 0.f), 255.f);
        const float l11 = l_11[bin];
        const float l12 = l_12[bin];
        const float l21 = l_21[bin];
        const float l22 = l_22[bin];
        const float top = l11 * (1.0f - xa) + l12 * xa;
        const float bot = l21 * (1.0f - xa) + l22 * xa;
        const float r   = top * (1.0f - ya) + bot * ya;
        res[j] = fminf(fmaxf(rintf(r), 0.f), 255.f);
    }
    *reinterpret_cast<float4*>(out + p) = make_float4(res[0], res[1], res[2], res[3]);
}

extern "C" void kernel_launch(void* const* d_in, const int* in_sizes, int n_in,
                              void* d_out, int out_size, void* d_ws, size_t ws_size,
                              hipStream_t stream) {
    const float* img = (const float*)d_in[0];
    float* out = (float*)d_out;
    float* lut = (float*)d_ws;                 // 512 * 256 * 4 B = 512 KiB

    clahe_hist_lut<<<IMG_B * GY * GX, 256, 0, stream>>>(img, lut);

    const int total_px = IMG_B * IMG_H * IMG_W;          // 33,554,432
    const int nthreads = total_px / 4;                   // 8,388,608
    clahe_apply<<<nthreads / 256, 256, 0, stream>>>(img, lut, out);
}

// Round 2
// 80.109 us; speedup vs baseline: 1.8445x; 1.8445x over previous
//
#include <hip/hip_runtime.h>

#define NB 256
#define CLIP_LIM 1024              // max(int(4.0*65536/256),1)
#define TSTRIDE 11                 // padded LDS table stride (gcd(11,32)=1)

// ---------------- Kernel 1: per-tile histogram -> clip/redistribute -> cdf -> LUT
// one block (1024 thr, 16 waves) per tile; optionally writes packed u8 bins
template <bool WRITE_BINS>
__global__ __launch_bounds__(1024) void clahe_hist_lut(const float* __restrict__ img,
                                                       float* __restrict__ lut,
                                                       unsigned int* __restrict__ bins) {
    const int t   = blockIdx.x;          // 0..511  (b*64 + ty*8 + tx)
    const int b   = t >> 6;
    const int ty  = (t >> 3) & 7;
    const int tx  = t & 7;
    const int tid = threadIdx.x;
    const int wv  = tid >> 6;            // wave id 0..15

    __shared__ int h[16 * NB];           // per-wave sub-histograms (16 KB)
    __shared__ int c[NB];
    __shared__ int s_excess;

    #pragma unroll
    for (int k = 0; k < 4; ++k) h[tid + k * 1024] = 0;
    if (tid == 0) s_excess = 0;
    __syncthreads();

    const float* base = img + ((size_t)b << 22) + (size_t)(ty * 256) * 2048 + tx * 256;
    unsigned int* bbase = bins + ((size_t)b << 20) + ty * 131072 + tx * 64;
    int* hw = &h[wv * NB];

    // 16384 float4 per tile; 16 iterations of 1024 threads, coalesced (1 row = 1 wave-load)
    for (int i = tid; i < 16384; i += 1024) {
        const int r = i >> 6;            // tile row 0..255
        const int q = i & 63;            // float4 column
        const float4 v = *reinterpret_cast<const float4*>(base + (size_t)r * 2048 + q * 4);
        const int b0 = (int)fminf(fmaxf(v.x, 0.f), 255.f);
        const int b1 = (int)fminf(fmaxf(v.y, 0.f), 255.f);
        const int b2 = (int)fminf(fmaxf(v.z, 0.f), 255.f);
        const int b3 = (int)fminf(fmaxf(v.w, 0.f), 255.f);
        atomicAdd(&hw[b0], 1);
        atomicAdd(&hw[b1], 1);
        atomicAdd(&hw[b2], 1);
        atomicAdd(&hw[b3], 1);
        if (WRITE_BINS)
            bbase[r * 512 + q] = (unsigned)b0 | ((unsigned)b1 << 8) |
                                 ((unsigned)b2 << 16) | ((unsigned)b3 << 24);
    }
    __syncthreads();

    // merge 16 sub-histograms, clip, accumulate excess (bins handled by tid<256)
    int clipped = 0;
    if (tid < NB) {
        int sum = 0;
        #pragma unroll
        for (int w = 0; w < 16; ++w) sum += h[w * NB + tid];
        clipped = min(sum, CLIP_LIM);
        atomicAdd(&s_excess, sum - clipped);
    }
    __syncthreads();

    if (tid < NB) {
        const int excess   = s_excess;
        const int add      = excess >> 8;
        const int residual = excess & 255;
        int step = 256 / (residual > 0 ? residual : 1);
        if (step < 1) step = 1;
        c[tid] = clipped + add + ((residual > 0 && (tid % step) == 0) ? 1 : 0);
    }
    __syncthreads();

    // inclusive Hillis-Steele scan over 256 bins (all threads hit barriers)
    #pragma unroll
    for (int off = 1; off < NB; off <<= 1) {
        int v = 0;
        if (tid < NB && tid >= off) v = c[tid - off];
        __syncthreads();
        if (tid < NB) c[tid] += v;
        __syncthreads();
    }

    if (tid < NB) {
        float lv = rintf((float)c[tid] * (255.0f / 65536.0f));  // exact; RTE matches jnp.round
        lut[t * NB + tid] = fminf(fmaxf(lv, 0.f), 255.f);
    }
}

// ---------------- Kernel 2: bilinear LUT apply via LDS y-blended padded tables
// one block per (image, row-pair); per pixel: ONE ds_read2_b32 + blend.
// Table: T[r][bin][k], k=0..9, where col k = lut_y[clip(k-1,0,7)]; segment s=floor(xf)+1
// picks cols (s,s+1). All arithmetic exact in fp32 (ints x k/256 weights) -> bitwise ref match.
template <bool USE_BINS>
__global__ __launch_bounds__(256) void clahe_apply(const float* __restrict__ img,
                                                   const unsigned int* __restrict__ bins,
                                                   const float* __restrict__ lut,
                                                   float* __restrict__ out) {
    const int bi  = blockIdx.x;
    const int b   = bi >> 10;
    const int y0  = (bi & 1023) * 2;     // row pair; never straddles a y-segment boundary
    const int tid = threadIdx.x;

    __shared__ float T[2 * NB * TSTRIDE];   // 22528 B

    {   // ---- build y-blended tables for both rows (tid == bin)
        const float yf  = (float)y0 * (1.0f / 256.0f) - 0.5f;
        const float y1f = floorf(yf);
        const int y1 = min(max((int)y1f, 0), 7);
        const int y2 = min(max((int)y1f + 1, 0), 7);
        const float* lb = lut + ((size_t)b << 14);
        float la[8], lc[8];
        #pragma unroll
        for (int xc = 0; xc < 8; ++xc) {
            la[xc] = lb[(y1 * 8 + xc) * NB + tid];
            lc[xc] = lb[(y2 * 8 + xc) * NB + tid];
        }
        #pragma unroll
        for (int r = 0; r < 2; ++r) {
            const float yfr = (float)(y0 + r) * (1.0f / 256.0f) - 0.5f;
            const float ya  = yfr - floorf(yfr);
            float* Tr = &T[r * NB * TSTRIDE + tid * TSTRIDE];
            #pragma unroll
            for (int k = 0; k < 10; ++k) {
                const int kc = (k == 0) ? 0 : ((k - 1 > 7) ? 7 : k - 1);
                Tr[k] = la[kc] * (1.0f - ya) + lc[kc] * ya;   // exact
            }
        }
    }
    __syncthreads();

    const size_t imgbase = ((size_t)b << 22) + (size_t)y0 * 2048;
    #pragma unroll
    for (int it = 0; it < 4; ++it) {
        const int r = it >> 1;
        const int i = (it & 1) * 256 + tid;          // float4-word index in row, 0..511
        const size_t prow = imgbase + (size_t)r * 2048;
        unsigned int w = 0;
        float4 vv;
        if constexpr (USE_BINS) {
            w = bins[(prow >> 2) + i];
        } else {
            vv = *reinterpret_cast<const float4*>(img + prow + i * 4);
        }
        const float* Tr = &T[r * NB * TSTRIDE];
        float res[4];
        #pragma unroll
        for (int j = 0; j < 4; ++j) {
            const int x    = i * 4 + j;
            const float xf = (float)x * (1.0f / 256.0f) - 0.5f;
            const float fl = floorf(xf);
            const float xa = xf - fl;
            const int s    = (int)fl + 1;            // 0..8
            int bn;
            if constexpr (USE_BINS) {
                bn = (w >> (8 * j)) & 255;
            } else {
                const float pv = (j == 0) ? vv.x : (j == 1) ? vv.y : (j == 2) ? vv.z : vv.w;
                bn = (int)fminf(fmaxf(pv, 0.f), 255.f);
            }
            const float* p  = &Tr[bn * TSTRIDE + s];
            const float a   = p[0];
            const float b2  = p[1];                  // ds_read2_b32 pair
            const float v   = a + (b2 - a) * xa;     // exact
            res[j] = fminf(fmaxf(rintf(v), 0.f), 255.f);
        }
        *reinterpret_cast<float4*>(out + prow + i * 4) = make_float4(res[0], res[1], res[2], res[3]);
    }
}

extern "C" void kernel_launch(void* const* d_in, const int* in_sizes, int n_in,
                              void* d_out, int out_size, void* d_ws, size_t ws_size,
                              hipStream_t stream) {
    const float* img = (const float*)d_in[0];
    float* out = (float*)d_out;
    float* lut = (float*)d_ws;                                    // 512 KiB
    unsigned int* bins = (unsigned int*)((char*)d_ws + 512 * 1024);
    const size_t need = 512 * 1024 + (size_t)8 * 2048 * 2048;     // LUT + packed u8 bins

    if (ws_size >= need) {
        clahe_hist_lut<true><<<512, 1024, 0, stream>>>(img, lut, bins);
        clahe_apply<true><<<8192, 256, 0, stream>>>(img, bins, lut, out);
    } else {
        clahe_hist_lut<false><<<512, 1024, 0, stream>>>(img, lut, nullptr);
        clahe_apply<false><<<8192, 256, 0, stream>>>(img, nullptr, lut, out);
    }
}

// Round 4
// 79.792 us; speedup vs baseline: 1.8518x; 1.0040x over previous
//
#include <hip/hip_runtime.h>

#define NB 256
#define CLIP_LIM 1024              // max(int(4.0*65536/256),1)
#define TSTRIDE 11                 // padded LDS table stride (gcd(11,32)=1)
#define HSTRIDE 264                // 256+8: adjacent sub-hists shift bank pattern by 8
#define NSUB 32                    // 2 sub-histograms per wave (lane parity)
#define ROWS 4                     // rows per apply block (aligned 4-row groups never straddle y-segment)

typedef float f32x4 __attribute__((ext_vector_type(4)));   // native vector for nontemporal builtins

// ---------------- Kernel 1: per-tile histogram -> clip/redistribute -> cdf -> LUT (+ packed u8 bins)
__global__ __launch_bounds__(1024) void clahe_hist_lut(const float* __restrict__ img,
                                                       float* __restrict__ lut,
                                                       unsigned int* __restrict__ bins) {
    const int t   = blockIdx.x;          // 0..511  (b*64 + ty*8 + tx)
    const int b   = t >> 6;
    const int ty  = (t >> 3) & 7;
    const int tx  = t & 7;
    const int tid = threadIdx.x;
    const int sub = ((tid >> 6) << 1) | (tid & 1);   // 0..31: wave*2 + lane parity

    __shared__ int h[NSUB * HSTRIDE];    // 33,792 B
    __shared__ int c[NB];
    __shared__ int s_excess;

    #pragma unroll
    for (int k = 0; k < 9; ++k) {
        const int idx = tid + k * 1024;
        if (idx < NSUB * HSTRIDE) h[idx] = 0;
    }
    if (tid == 0) s_excess = 0;
    __syncthreads();

    const float* base = img + ((size_t)b << 22) + (size_t)(ty * 256) * 2048 + tx * 256;
    unsigned int* bbase = bins + ((size_t)b << 20) + ty * 131072 + tx * 64;
    int* hw = &h[sub * HSTRIDE];

    // 16384 float4 per tile; 16 iterations of 1024 threads, coalesced (1 row = 4 wave-rows)
    for (int i = tid; i < 16384; i += 1024) {
        const int r = i >> 6;            // tile row 0..255
        const int q = i & 63;            // float4 column
        const f32x4 v = __builtin_nontemporal_load(
            reinterpret_cast<const f32x4*>(base + (size_t)r * 2048 + q * 4));
        const int b0 = (int)fminf(fmaxf(v.x, 0.f), 255.f);
        const int b1 = (int)fminf(fmaxf(v.y, 0.f), 255.f);
        const int b2 = (int)fminf(fmaxf(v.z, 0.f), 255.f);
        const int b3 = (int)fminf(fmaxf(v.w, 0.f), 255.f);
        atomicAdd(&hw[b0], 1);
        atomicAdd(&hw[b1], 1);
        atomicAdd(&hw[b2], 1);
        atomicAdd(&hw[b3], 1);
        bbase[r * 512 + q] = (unsigned)b0 | ((unsigned)b1 << 8) |
                             ((unsigned)b2 << 16) | ((unsigned)b3 << 24);
    }
    __syncthreads();

    // merge 32 sub-histograms, clip, accumulate excess
    int clipped = 0;
    if (tid < NB) {
        int sum = 0;
        #pragma unroll
        for (int w = 0; w < NSUB; ++w) sum += h[w * HSTRIDE + tid];
        clipped = min(sum, CLIP_LIM);
        atomicAdd(&s_excess, sum - clipped);
    }
    __syncthreads();

    if (tid < NB) {
        const int excess   = s_excess;
        const int add      = excess >> 8;
        const int residual = excess & 255;
        int step = 256 / (residual > 0 ? residual : 1);
        if (step < 1) step = 1;
        c[tid] = clipped + add + ((residual > 0 && (tid % step) == 0) ? 1 : 0);
    }
    __syncthreads();

    // inclusive Hillis-Steele scan over 256 bins (all threads hit barriers)
    #pragma unroll
    for (int off = 1; off < NB; off <<= 1) {
        int v = 0;
        if (tid < NB && tid >= off) v = c[tid - off];
        __syncthreads();
        if (tid < NB) c[tid] += v;
        __syncthreads();
    }

    if (tid < NB) {
        float lv = rintf((float)c[tid] * (255.0f / 65536.0f));  // exact; RTE matches jnp.round
        lut[t * NB + tid] = fminf(fmaxf(lv, 0.f), 255.f);
    }
}

// ---------------- Kernel 2: bilinear LUT apply via LDS y-blended padded tables
// One block per (image, 4-row group); per pixel: ONE ds_read2_b32 + exact blend.
// T[r][bin][k], k=0..9: col k = lut_yblend[clip(k-1,0,7)]; segment s=floor(xf)+1 -> cols (s,s+1).
__global__ __launch_bounds__(256) void clahe_apply(const unsigned int* __restrict__ bins,
                                                   const float* __restrict__ lut,
                                                   float* __restrict__ out) {
    const int bi  = blockIdx.x;
    const int b   = bi >> 9;
    const int y0  = (bi & 511) * ROWS;
    const int tid = threadIdx.x;

    __shared__ float T[ROWS * NB * TSTRIDE];   // 45,056 B

    {   // ---- build y-blended tables for ROWS rows (tid == bin)
        const float yf  = (float)y0 * (1.0f / 256.0f) - 0.5f;
        const float y1f = floorf(yf);
        const int y1 = min(max((int)y1f, 0), 7);
        const int y2 = min(max((int)y1f + 1, 0), 7);
        const float* lb = lut + ((size_t)b << 14);
        float la[8], lc[8];
        #pragma unroll
        for (int xc = 0; xc < 8; ++xc) {
            la[xc] = lb[(y1 * 8 + xc) * NB + tid];
            lc[xc] = lb[(y2 * 8 + xc) * NB + tid];
        }
        #pragma unroll
        for (int r = 0; r < ROWS; ++r) {
            const float yfr = (float)(y0 + r) * (1.0f / 256.0f) - 0.5f;
            const float ya  = yfr - floorf(yfr);
            float* Tr = &T[r * NB * TSTRIDE + tid * TSTRIDE];
            #pragma unroll
            for (int k = 0; k < 10; ++k) {
                const int kc = (k == 0) ? 0 : ((k - 1 > 7) ? 7 : k - 1);
                Tr[k] = la[kc] * (1.0f - ya) + lc[kc] * ya;   // exact (ints x k/256 weights)
            }
        }
    }
    __syncthreads();

    const size_t imgbase = ((size_t)b << 22) + (size_t)y0 * 2048;
    #pragma unroll
    for (int it = 0; it < 2 * ROWS; ++it) {
        const int r = it >> 1;
        const int i = (it & 1) * 256 + tid;          // float4-word index in row, 0..511
        const size_t prow = imgbase + (size_t)r * 2048;
        const unsigned int w = bins[(prow >> 2) + i];
        const float* Tr = &T[r * NB * TSTRIDE];
        float res[4];
        #pragma unroll
        for (int j = 0; j < 4; ++j) {
            const int x    = i * 4 + j;
            const float xf = (float)x * (1.0f / 256.0f) - 0.5f;
            const float fl = floorf(xf);
            const float xa = xf - fl;
            const int s    = (int)fl + 1;            // 0..8
            const int bn   = (w >> (8 * j)) & 255;
            const float* p = &Tr[bn * TSTRIDE + s];
            const float a  = p[0];
            const float b2 = p[1];                   // ds_read2_b32 pair
            const float v  = a + (b2 - a) * xa;      // exact
            res[j] = fminf(fmaxf(rintf(v), 0.f), 255.f);
        }
        const f32x4 o = { res[0], res[1], res[2], res[3] };
        __builtin_nontemporal_store(o, reinterpret_cast<f32x4*>(out + prow + i * 4));
    }
}

extern "C" void kernel_launch(void* const* d_in, const int* in_sizes, int n_in,
                              void* d_out, int out_size, void* d_ws, size_t ws_size,
                              hipStream_t stream) {
    const float* img = (const float*)d_in[0];
    float* out = (float*)d_out;
    float* lut = (float*)d_ws;                                    // 512 KiB
    unsigned int* bins = (unsigned int*)((char*)d_ws + 512 * 1024);

    clahe_hist_lut<<<512, 1024, 0, stream>>>(img, lut, bins);
    clahe_apply<<<8 * (2048 / ROWS), 256, 0, stream>>>(bins, lut, out);
}